// Round 1
// baseline (163.671 us; speedup 1.0000x reference)
//
#include <hip/hip_runtime.h>
#include <math.h>

// ---- problem constants (match reference exactly) ----
#define NATOMS 600
#define NBINS  64
#define NBATCH 4

constexpr float CELL_L    = 20.0f;
constexpr float HALF_CELL = 10.0f;
constexpr float BIN_W     = 7.5f / 64.0f;          // 0.1171875, exact in f32
constexpr float CUTOFF_ADJ = 7.5f + 2.0f * BIN_W;  // 7.734375, exact
constexpr float CUT2      = CUTOFF_ADJ * CUTOFF_ADJ; // 59.820556640625, exact in f32
constexpr float G_SPACING = 7.5f / 63.0f;          // GaussianSmearing width
constexpr float G_COEFF   = -0.5f / (G_SPACING * G_SPACING);
constexpr float PI_F      = 3.14159265358979323846f;

// Kernel 1: soft-histogram accumulation.
// 4 waves/block, wave = one (b,i) row, lane = one bin.
// 600 blocks -> 2400 rows = B*N. Block b-range: 150 blocks per batch (600%4==0
// so all 4 rows of a block share one batch).
__global__ __launch_bounds__(256) void rdf_pairs(const float* __restrict__ xyz,
                                                 float* __restrict__ count_ws) {
    __shared__ float sx[NATOMS], sy[NATOMS], sz[NATOMS];
    __shared__ float shist[NBINS];

    const int wave = threadIdx.x >> 6;
    const int lane = threadIdx.x & 63;
    const int row  = blockIdx.x * 4 + wave;        // [0, 2400)
    const int b    = row / NATOMS;                 // uniform across block
    const int i    = row - b * NATOMS;

    // stage this batch's coordinates into LDS (1800 floats = 7.2 KB)
    const float* g = xyz + (size_t)b * NATOMS * 3;
    for (int t = threadIdx.x; t < NATOMS; t += 256) {
        sx[t] = g[3 * t + 0];
        sy[t] = g[3 * t + 1];
        sz[t] = g[3 * t + 2];
    }
    if (threadIdx.x < NBINS) shist[threadIdx.x] = 0.0f;
    __syncthreads();

    const float xi = sx[i], yi = sy[i], zi = sz[i];
    const float off = (float)lane * G_SPACING;
    float acc = 0.0f;

    for (int j = 0; j < NATOMS; ++j) {
        // dis_mat[b,i,j] = xyz[b,j] - xyz[b,i], minimum-image wrap
        float dx = sx[j] - xi;
        float dy = sy[j] - yi;
        float dz = sz[j] - zi;
        dx += (dx < -HALF_CELL ? CELL_L : 0.0f) - (dx >= HALF_CELL ? CELL_L : 0.0f);
        dy += (dy < -HALF_CELL ? CELL_L : 0.0f) - (dy >= HALF_CELL ? CELL_L : 0.0f);
        dz += (dz < -HALF_CELL ? CELL_L : 0.0f) - (dz >= HALF_CELL ? CELL_L : 0.0f);
        float r2 = dx * dx + dy * dy + dz * dz;
        // wave-uniform branch: every lane sees the same (b,i,j)
        if (r2 < CUT2 && r2 != 0.0f) {
            float d = sqrtf(r2);
            float t = d - off;
            acc += __expf(G_COEFF * t * t);
        }
    }

    // per-wave -> per-block -> global reduction
    atomicAdd(&shist[lane], acc);
    __syncthreads();
    if (threadIdx.x < NBINS) atomicAdd(&count_ws[threadIdx.x], shist[threadIdx.x]);
}

// Kernel 2: normalize and emit (BINS[65], rdf[64]) = 129 floats.
__global__ __launch_bounds__(64) void rdf_finalize(const float* __restrict__ count_ws,
                                                   float* __restrict__ out) {
    const int lane = threadIdx.x;  // 0..63
    float c = count_ws[lane];

    // wave-wide sum across 64 lanes
    float total = c;
    #pragma unroll
    for (int o = 32; o > 0; o >>= 1) total += __shfl_xor(total, o, 64);

    // BINS = linspace(0, 7.5, 65)
    out[lane] = (float)lane * BIN_W;
    if (lane == 0) out[64] = 7.5f;

    const float b0 = (float)lane * BIN_W;
    const float b1 = (float)(lane + 1) * BIN_W;
    const float vol = (4.0f * PI_F / 3.0f) * (b1 * b1 * b1 - b0 * b0 * b0);
    const float diam = 2.0f * CUTOFF_ADJ;
    const float denom = 2.0f * vol / (diam * diam * diam);
    out[65 + lane] = (c / total) / denom;
}

extern "C" void kernel_launch(void* const* d_in, const int* in_sizes, int n_in,
                              void* d_out, int out_size, void* d_ws, size_t ws_size,
                              hipStream_t stream) {
    const float* xyz = (const float*)d_in[0];   // [4, 600, 3] f32
    float* out = (float*)d_out;                 // 129 f32
    float* cnt = (float*)d_ws;                  // 64 f32 accumulator

    hipMemsetAsync(cnt, 0, NBINS * sizeof(float), stream);
    rdf_pairs<<<dim3(NBATCH * NATOMS / 4), dim3(256), 0, stream>>>(xyz, cnt);
    rdf_finalize<<<dim3(1), dim3(64), 0, stream>>>(cnt, out);
}

// Round 2
// 120.182 us; speedup vs baseline: 1.3619x; 1.3619x over previous
//
#include <hip/hip_runtime.h>
#include <math.h>

// ---- problem constants (match reference exactly) ----
#define NATOMS 600
#define NBINS  64
#define NBATCH 4

constexpr float CELL_L     = 20.0f;
constexpr float INV_CELL   = 1.0f / 20.0f;
constexpr float BIN_W      = 7.5f / 64.0f;           // 0.1171875, exact in f32
constexpr float CUTOFF_ADJ = 7.5f + 2.0f * BIN_W;    // 7.734375, exact
constexpr float CUT2       = CUTOFF_ADJ * CUTOFF_ADJ;// 59.820556640625, exact
constexpr float G_SPACING  = 7.5f / 63.0f;           // GaussianSmearing width
constexpr float G_COEFF    = -0.5f / (G_SPACING * G_SPACING);
constexpr float PI_F       = 3.14159265358979323846f;

#define JSPLIT 4   // waves per row; each wave covers 150 j's

// Kernel 1: soft-histogram accumulation.
// Grid: 2400 blocks (one per (b,i) row), 256 threads = 4 waves, wave w covers
// j in [w*150, w*150+150). Distance phase: lane = j within a 64-tile (all
// lanes distinct pairs). Gaussian phase: lane = bin; in-cutoff distances are
// broadcast one at a time via readlane from the ballot mask.
__global__ __launch_bounds__(256) void rdf_pairs(const float* __restrict__ xyz,
                                                 float* __restrict__ count_ws) {
    __shared__ float sflat[NATOMS * 3];   // this batch's coords, flat
    __shared__ float shist[256];

    const int tid  = threadIdx.x;
    const int wave = tid >> 6;
    const int lane = tid & 63;
    const int row  = blockIdx.x;          // [0, 2400)
    const int b    = row / NATOMS;
    const int i    = row - b * NATOMS;

    // stage batch coords (1800 floats, coalesced)
    const float* g = xyz + (size_t)b * NATOMS * 3;
    for (int t = tid; t < NATOMS * 3; t += 256) sflat[t] = g[t];
    __syncthreads();

    const float xi = sflat[3 * i + 0];
    const float yi = sflat[3 * i + 1];
    const float zi = sflat[3 * i + 2];
    const float off = (float)lane * G_SPACING;   // lane = bin center
    float acc = 0.0f;

    const int jbeg = wave * (NATOMS / JSPLIT);
    const int jend = jbeg + (NATOMS / JSPLIT);

    for (int j0 = jbeg; j0 < jend; j0 += 64) {
        const int j = j0 + lane;
        const bool valid = j < jend;
        const int jj = valid ? j : 0;
        // per-lane pair distance (lane = j here)
        float dx = sflat[3 * jj + 0] - xi;
        float dy = sflat[3 * jj + 1] - yi;
        float dz = sflat[3 * jj + 2] - zi;
        // minimum-image wrap: dx -= L*rint(dx/L). Exactly r^2-equivalent to
        // the reference's two-sided branch form (boundary ties flip sign only).
        dx -= CELL_L * rintf(dx * INV_CELL);
        dy -= CELL_L * rintf(dy * INV_CELL);
        dz -= CELL_L * rintf(dz * INV_CELL);
        const float r2 = dx * dx + dy * dy + dz * dz;
        const float d  = sqrtf(r2);
        unsigned long long m =
            __ballot(valid && (r2 < CUT2) && (r2 != 0.0f));
        // bit-scan the in-cutoff set; broadcast each distance, lanes = bins
        while (m) {
            const int k = (int)__builtin_ctzll(m);
            m &= m - 1;
            const float dk = __int_as_float(
                __builtin_amdgcn_readlane(__float_as_int(d), k));
            const float t = dk - off;
            acc += __expf(G_COEFF * t * t);
        }
    }

    // block reduction (4 waves -> 64 bins), one global atomic wave per block
    shist[tid] = acc;
    __syncthreads();
    if (tid < NBINS) {
        const float s = shist[tid] + shist[64 + tid] + shist[128 + tid] +
                        shist[192 + tid];
        atomicAdd(&count_ws[tid], s);
    }
}

// Kernel 2: normalize and emit (BINS[65], rdf[64]) = 129 floats.
__global__ __launch_bounds__(64) void rdf_finalize(const float* __restrict__ count_ws,
                                                   float* __restrict__ out) {
    const int lane = threadIdx.x;  // 0..63
    const float c = count_ws[lane];

    float total = c;
    #pragma unroll
    for (int o = 32; o > 0; o >>= 1) total += __shfl_xor(total, o, 64);

    out[lane] = (float)lane * BIN_W;           // BINS = linspace(0, 7.5, 65)
    if (lane == 0) out[64] = 7.5f;

    const float b0 = (float)lane * BIN_W;
    const float b1 = (float)(lane + 1) * BIN_W;
    const float vol = (4.0f * PI_F / 3.0f) * (b1 * b1 * b1 - b0 * b0 * b0);
    const float diam = 2.0f * CUTOFF_ADJ;
    const float denom = 2.0f * vol / (diam * diam * diam);
    out[65 + lane] = (c / total) / denom;
}

extern "C" void kernel_launch(void* const* d_in, const int* in_sizes, int n_in,
                              void* d_out, int out_size, void* d_ws, size_t ws_size,
                              hipStream_t stream) {
    const float* xyz = (const float*)d_in[0];   // [4, 600, 3] f32
    float* out = (float*)d_out;                 // 129 f32
    float* cnt = (float*)d_ws;                  // 64 f32 accumulator

    hipMemsetAsync(cnt, 0, NBINS * sizeof(float), stream);
    rdf_pairs<<<dim3(NBATCH * NATOMS), dim3(256), 0, stream>>>(xyz, cnt);
    rdf_finalize<<<dim3(1), dim3(64), 0, stream>>>(cnt, out);
}